// Round 8
// baseline (1717.714 us; speedup 1.0000x reference)
//
#include <hip/hip_runtime.h>
#include <cstddef>

// ---------- types ----------
typedef _Float16 f16x8 __attribute__((ext_vector_type(8)));
typedef short    s16x8 __attribute__((ext_vector_type(8)));
typedef short    s16x4 __attribute__((ext_vector_type(4)));
typedef float    f32x4 __attribute__((ext_vector_type(4)));

#define MFMA_F16(a, b, c) __builtin_amdgcn_mfma_f32_16x16x32_f16((a), (b), (c), 0, 0, 0)

#if __has_builtin(__builtin_amdgcn_sched_barrier)
#define SCHED_FENCE() __builtin_amdgcn_sched_barrier(0)
#else
#define SCHED_FENCE() do {} while (0)
#endif

#if __has_builtin(__builtin_amdgcn_rcpf)
__device__ __forceinline__ float fast_rcp(float x) { return __builtin_amdgcn_rcpf(x); }
#else
__device__ __forceinline__ float fast_rcp(float x) { return 1.f / x; }
#endif

__device__ __forceinline__ f16x8 ld8(const short* p) {
  return __builtin_bit_cast(f16x8, *(const s16x8*)p);
}
__device__ __forceinline__ float s2f(short s) {
  return (float)__builtin_bit_cast(_Float16, s);
}
__device__ __forceinline__ short f2s(float f) {
  return __builtin_bit_cast(short, (_Float16)f);
}

// GRU gate math (shared). Returns h_new.
__device__ __forceinline__ float gru_gate(float rpre, float zpre, float ghn,
                                          float xnb, float hprev) {
  const float rg = fast_rcp(1.f + __expf(-rpre));
  const float zg = fast_rcp(1.f + __expf(-zpre));
  const float narg = xnb + rg * ghn;
  const float e2 = __expf(2.f * narg);
  const float ng = 1.f - 2.f * fast_rcp(e2 + 1.f);  // tanh(narg)
  return (1.f - zg) * ng + zg * hprev;
}

// ---------- fp32 -> fp16 casts (weights only), one launch ----------
struct CastDesc { const float* src; short* dst; int n; };
struct CastArgs { CastDesc d[6]; };

__global__ void cast_many(CastArgs a) {
  const int tid = blockIdx.x * blockDim.x + threadIdx.x;
  const int stride = gridDim.x * blockDim.x;
#pragma unroll
  for (int j = 0; j < 6; j++) {
    const float* __restrict__ s = a.d[j].src;
    short* __restrict__ o = a.d[j].dst;
    const int n = a.d[j].n;
    for (int i = tid; i < n; i += stride) o[i] = f2s(s[i]);
  }
}

// ---------- xg projection GEMM (chunked) ----------
// xgT[(wg*TC + t)][c*16+p][q*4+r] = (A_chunk[t] @ W^T) for batch row q*4+r of
// wg's 16-row tile — exactly the rec kernel's epilogue C-layout, so rec reads
// one coalesced s16x4 per (gate, jt). A: [B, TC, K] fp16 chunk. W: [NC, K].
template <int K, int NC, int TC>
__global__ __launch_bounds__(256)
void xg_gemm(const short* __restrict__ A, const short* __restrict__ W,
             short* __restrict__ xgT) {
  constexpr int KF = K / 32;
  const int lane = threadIdx.x & 63, wid = threadIdx.x >> 6;
  const int p = lane & 15, q = lane >> 4;
  const int t = blockIdx.x, wg = blockIdx.y;
  const int b0 = wg * 16;

  const short* ap = A + ((size_t)(b0 + p) * TC + t) * K + q * 8;
  f16x8 ax[KF];
#pragma unroll
  for (int k = 0; k < KF; k++) ax[k] = ld8(ap + k * 32);

  short* outb = xgT + ((size_t)wg * TC + t) * NC * 16;
#pragma unroll 1
  for (int c = wid; c < NC / 16; c += 4) {
    const short* wp = W + (size_t)(c * 16 + p) * K + q * 8;
    f32x4 acc = {0.f, 0.f, 0.f, 0.f};
#pragma unroll
    for (int k = 0; k < KF; k++) acc = MFMA_F16(ax[k], ld8(wp + k * 32), acc);
    s16x4 o;
#pragma unroll
    for (int r = 0; r < 4; r++) o[r] = f2s(acc[r]);
    *(s16x4*)&outb[(size_t)(c * 16 + p) * 16 + q * 4] = o;
  }
}

// ---------- L1 recurrence (fused input projection), chunked ----------
// H=256, 8 waves, JT=2. whh_n LDS-resident; whh_r/z + wih + x(fp32) streamed
// per step (issue-early). h carried across chunks via fp32 carry[B,256].
template <int TC>
__global__ __launch_bounds__(512)
void gru_l1(const float* __restrict__ x,     // [B,256,64] fp32
            const short* __restrict__ Wih,   // [768,64] fp16
            const short* __restrict__ Whh,   // [768,256] fp16
            const float* __restrict__ b_ih, const float* __restrict__ b_hh,
            short* __restrict__ h1c,         // [B,TC,256] fp16 chunk out
            float* __restrict__ carry,       // [B,256] fp32
            int t0) {
  constexpr int H = 256, NW = 8, JT = 2, KS = 8, KSI = 2, HP = H + 8;
  constexpr int T = 256, F = 64;
  extern __shared__ __align__(16) short smem[];
  short* whhL = smem;             // [256][HP]  (n-gate rows)
  short* hb   = smem + H * HP;    // [2][16][HP]

  const int tid = threadIdx.x, lane = tid & 63, wid = tid >> 6;
  const int p = lane & 15, q = lane >> 4;
  const int b0 = blockIdx.x * 16, j0 = wid * (16 * JT);

  for (int i = tid; i < H * (H / 8); i += NW * 64) {
    const int row = i / (H / 8), kc = i % (H / 8);
    *(s16x8*)&whhL[row * HP + kc * 8] =
        *(const s16x8*)&Whh[(size_t)(2 * H + row) * H + kc * 8];
  }
  if (t0 == 0) {
    for (int i = tid; i < 2 * 16 * HP; i += NW * 64) hb[i] = 0;
  } else {
    for (int i = tid; i < 16 * H; i += NW * 64) {
      const int row = i >> 8, col = i & (H - 1);
      hb[row * HP + col] = f2s(carry[(size_t)(b0 + row) * H + col]);
    }
  }

  float brz_r[JT], brz_z[JT], bxn[JT], bhn[JT];
  const short* wrz[2][JT];
  const short* wih_p[3][JT];
  int wrow[JT];
#pragma unroll
  for (int jt = 0; jt < JT; jt++) {
    const int col = j0 + jt * 16 + p;
    brz_r[jt] = b_ih[col] + b_hh[col];
    brz_z[jt] = b_ih[H + col] + b_hh[H + col];
    bxn[jt]   = b_ih[2 * H + col];
    bhn[jt]   = b_hh[2 * H + col];
    wrow[jt]  = col;
    wrz[0][jt] = Whh + (size_t)(0 * H + col) * H + q * 8;
    wrz[1][jt] = Whh + (size_t)(1 * H + col) * H + q * 8;
#pragma unroll
    for (int g = 0; g < 3; g++)
      wih_p[g][jt] = Wih + (size_t)(g * H + col) * F + q * 8;
  }
  float hprev[JT][4];
#pragma unroll
  for (int jt = 0; jt < JT; jt++)
#pragma unroll
    for (int r = 0; r < 4; r++)
      hprev[jt][r] = (t0 == 0) ? 0.f
                   : carry[(size_t)(b0 + q * 4 + r) * H + j0 + jt * 16 + p];

  __syncthreads();

  for (int t = 0; t < TC; t++) {
    const int cur = t & 1;
    short* hbc = hb + cur * 16 * HP;
    short* hbn = hb + (cur ^ 1) * 16 * HP;

    // issue-early: whh r/z + wih streams + x (fp32, converted)
    f16x8 wst[2][JT][KS];
#pragma unroll
    for (int g = 0; g < 2; g++)
#pragma unroll
      for (int jt = 0; jt < JT; jt++)
#pragma unroll
        for (int k = 0; k < KS; k++) wst[g][jt][k] = ld8(wrz[g][jt] + k * 32);
    f16x8 wis[3][JT][KSI];
#pragma unroll
    for (int g = 0; g < 3; g++)
#pragma unroll
      for (int jt = 0; jt < JT; jt++)
#pragma unroll
        for (int k = 0; k < KSI; k++) wis[g][jt][k] = ld8(wih_p[g][jt] + k * 32);
    f16x8 axc[KSI];
    {
      const float* xp = x + ((size_t)(b0 + p) * T + (t0 + t)) * F + q * 8;
#pragma unroll
      for (int k = 0; k < KSI; k++) {
        const f32x4 a0 = *(const f32x4*)(xp + k * 32);
        const f32x4 a1 = *(const f32x4*)(xp + k * 32 + 4);
        f16x8 v;
#pragma unroll
        for (int i = 0; i < 4; i++) { v[i] = (_Float16)a0[i]; v[4 + i] = (_Float16)a1[i]; }
        axc[k] = v;
      }
    }
    SCHED_FENCE();

    f32x4 ar[JT], az[JT], an[JT], xa[JT];
#pragma unroll
    for (int jt = 0; jt < JT; jt++) {
      ar[jt] = f32x4{0.f, 0.f, 0.f, 0.f};
      az[jt] = f32x4{0.f, 0.f, 0.f, 0.f};
      an[jt] = f32x4{0.f, 0.f, 0.f, 0.f};
      xa[jt] = f32x4{0.f, 0.f, 0.f, 0.f};
    }
    f16x8 ah[KS];
#pragma unroll
    for (int k = 0; k < KS; k++) ah[k] = ld8(&hbc[p * HP + k * 32 + q * 8]);

    // n-gate from LDS first (covers stream latency)
#pragma unroll
    for (int k = 0; k < KS; k++)
#pragma unroll
      for (int jt = 0; jt < JT; jt++)
        an[jt] = MFMA_F16(ah[k], ld8(&whhL[wrow[jt] * HP + k * 32 + q * 8]), an[jt]);
    // streamed r/z
#pragma unroll
    for (int k = 0; k < KS; k++)
#pragma unroll
      for (int jt = 0; jt < JT; jt++) {
        ar[jt] = MFMA_F16(ah[k], wst[0][jt][k], ar[jt]);
        az[jt] = MFMA_F16(ah[k], wst[1][jt][k], az[jt]);
      }
    // input projection
#pragma unroll
    for (int k = 0; k < KSI; k++)
#pragma unroll
      for (int jt = 0; jt < JT; jt++) {
        ar[jt] = MFMA_F16(axc[k], wis[0][jt][k], ar[jt]);
        az[jt] = MFMA_F16(axc[k], wis[1][jt][k], az[jt]);
        xa[jt] = MFMA_F16(axc[k], wis[2][jt][k], xa[jt]);
      }

#pragma unroll
    for (int jt = 0; jt < JT; jt++)
#pragma unroll
      for (int r = 0; r < 4; r++) {
        const int bm = q * 4 + r;
        const int col = j0 + jt * 16 + p;
        const float hnew = gru_gate(ar[jt][r] + brz_r[jt], az[jt][r] + brz_z[jt],
                                    an[jt][r] + bhn[jt], xa[jt][r] + bxn[jt],
                                    hprev[jt][r]);
        hprev[jt][r] = hnew;
        const short hf = f2s(hnew);
        hbn[bm * HP + col] = hf;
        h1c[((size_t)(b0 + bm) * TC + t) * H + col] = hf;
      }
    __syncthreads();
  }
#pragma unroll
  for (int jt = 0; jt < JT; jt++)
#pragma unroll
    for (int r = 0; r < 4; r++)
      carry[(size_t)(b0 + q * 4 + r) * H + j0 + jt * 16 + p] = hprev[jt][r];
}

// ---------- L2/L3 recurrence: whh fully LDS-resident + precomputed xg ----------
template <int H, int NW, int JT, int TC, bool STORE_SEQ>
__global__ __launch_bounds__(NW * 64)
void gru_xg(const short* __restrict__ xgT,   // [(32*TC+1)][3H][16] fp16
            const short* __restrict__ Whh,   // [3H,H] fp16
            const float* __restrict__ b_ih, const float* __restrict__ b_hh,
            short* __restrict__ hseqc,       // [B,TC,H] fp16 (STORE_SEQ)
            float* __restrict__ carry,       // [B,H] fp32
            float* __restrict__ hlast,       // [B,H] fp32 (!STORE_SEQ)
            int t0) {
  static_assert(NW * 16 * JT == H, "tiling must cover H");
  constexpr int KS = H / 32, HP = H + 8;
  constexpr size_t XGS = (size_t)3 * H * 16;  // per-t stride
  extern __shared__ __align__(16) short smem[];
  short* whhL = smem;                 // [3H][HP]
  short* hb   = smem + 3 * H * HP;    // [2][16][HP]

  const int tid = threadIdx.x, lane = tid & 63, wid = tid >> 6;
  const int p = lane & 15, q = lane >> 4;
  const int wg = blockIdx.x, b0 = wg * 16, j0 = wid * (16 * JT);

  for (int i = tid; i < 3 * H * (H / 8); i += NW * 64) {
    const int row = i / (H / 8), kc = i % (H / 8);
    *(s16x8*)&whhL[row * HP + kc * 8] = *(const s16x8*)&Whh[(size_t)row * H + kc * 8];
  }
  if (t0 == 0) {
    for (int i = tid; i < 2 * 16 * HP; i += NW * 64) hb[i] = 0;
  } else {
    for (int i = tid; i < 16 * H; i += NW * 64) {
      const int row = i / H, col = i % H;
      hb[row * HP + col] = f2s(carry[(size_t)(b0 + row) * H + col]);
    }
  }

  float brz_r[JT], brz_z[JT], bxn[JT], bhn[JT];
  int wrow[JT];
  const short* xgp[3][JT];
#pragma unroll
  for (int jt = 0; jt < JT; jt++) {
    const int col = j0 + jt * 16 + p;
    brz_r[jt] = b_ih[col] + b_hh[col];
    brz_z[jt] = b_ih[H + col] + b_hh[H + col];
    bxn[jt]   = b_ih[2 * H + col];
    bhn[jt]   = b_hh[2 * H + col];
    wrow[jt]  = col;
#pragma unroll
    for (int g = 0; g < 3; g++)
      xgp[g][jt] = xgT + (size_t)wg * TC * XGS + (size_t)(g * H + col) * 16 + q * 4;
  }
  float hprev[JT][4];
#pragma unroll
  for (int jt = 0; jt < JT; jt++)
#pragma unroll
    for (int r = 0; r < 4; r++)
      hprev[jt][r] = (t0 == 0) ? 0.f
                   : carry[(size_t)(b0 + q * 4 + r) * H + j0 + jt * 16 + p];

  // prime xg prefetch (local t = 0)
  s16x4 xgc[3][JT];
#pragma unroll
  for (int g = 0; g < 3; g++)
#pragma unroll
    for (int jt = 0; jt < JT; jt++) xgc[g][jt] = *(const s16x4*)xgp[g][jt];

  __syncthreads();

  for (int t = 0; t < TC; t++) {
    const int cur = t & 1;
    short* hbc = hb + cur * 16 * HP;
    short* hbn = hb + (cur ^ 1) * 16 * HP;

    // prefetch next step's xg (t=TC-1 reads the +1 pad row: in-bounds, unused)
    s16x4 xgn[3][JT];
    {
      const size_t toff = (size_t)(t + 1) * XGS;
#pragma unroll
      for (int g = 0; g < 3; g++)
#pragma unroll
        for (int jt = 0; jt < JT; jt++)
          xgn[g][jt] = *(const s16x4*)(xgp[g][jt] + toff);
    }

    f32x4 ar[JT], az[JT], an[JT];
#pragma unroll
    for (int jt = 0; jt < JT; jt++) {
      ar[jt] = f32x4{0.f, 0.f, 0.f, 0.f};
      az[jt] = f32x4{0.f, 0.f, 0.f, 0.f};
      an[jt] = f32x4{0.f, 0.f, 0.f, 0.f};
    }
    f16x8 ah[KS];
#pragma unroll
    for (int k = 0; k < KS; k++) ah[k] = ld8(&hbc[p * HP + k * 32 + q * 8]);

#pragma unroll
    for (int k = 0; k < KS; k++)
#pragma unroll
      for (int jt = 0; jt < JT; jt++) {
        ar[jt] = MFMA_F16(ah[k], ld8(&whhL[(0 * H + wrow[jt]) * HP + k * 32 + q * 8]), ar[jt]);
        az[jt] = MFMA_F16(ah[k], ld8(&whhL[(1 * H + wrow[jt]) * HP + k * 32 + q * 8]), az[jt]);
        an[jt] = MFMA_F16(ah[k], ld8(&whhL[(2 * H + wrow[jt]) * HP + k * 32 + q * 8]), an[jt]);
      }

#pragma unroll
    for (int jt = 0; jt < JT; jt++)
#pragma unroll
      for (int r = 0; r < 4; r++) {
        const int bm = q * 4 + r;
        const int col = j0 + jt * 16 + p;
        const float hnew = gru_gate(ar[jt][r] + s2f(xgc[0][jt][r]) + brz_r[jt],
                                    az[jt][r] + s2f(xgc[1][jt][r]) + brz_z[jt],
                                    an[jt][r] + bhn[jt],
                                    s2f(xgc[2][jt][r]) + bxn[jt], hprev[jt][r]);
        hprev[jt][r] = hnew;
        const short hf = f2s(hnew);
        hbn[bm * HP + col] = hf;
        if (STORE_SEQ) {
          hseqc[((size_t)(b0 + bm) * TC + t) * H + col] = hf;
        } else if (t0 + t == 255) {
          hlast[(size_t)(b0 + bm) * H + col] = hnew;
        }
      }
#pragma unroll
    for (int g = 0; g < 3; g++)
#pragma unroll
      for (int jt = 0; jt < JT; jt++) xgc[g][jt] = xgn[g][jt];
    __syncthreads();
  }
#pragma unroll
  for (int jt = 0; jt < JT; jt++)
#pragma unroll
    for (int r = 0; r < 4; r++)
      carry[(size_t)(b0 + q * 4 + r) * H + j0 + jt * 16 + p] = hprev[jt][r];
}

// ---------- dense head ----------
__global__ void dense_kernel(const float* __restrict__ hl, const float* __restrict__ Wd,
                             const float* __restrict__ bd, float* __restrict__ out) {
  const int b = blockIdx.x * 64 + threadIdx.x;
  float a = bd[0];
#pragma unroll
  for (int k = 0; k < 64; k++) a = fmaf(hl[b * 64 + k], Wd[k], a);
  out[b] = a;
}

// ---------- host ----------
extern "C" void kernel_launch(void* const* d_in, const int* in_sizes, int n_in,
                              void* d_out, int out_size, void* d_ws, size_t ws_size,
                              hipStream_t stream) {
  constexpr int B = 512, T = 256;
  constexpr int H1 = 256, H2 = 128, H3 = 64, F = 64;
  constexpr int TC = 64, NCHUNK = T / TC;

  const float* x     = (const float*)d_in[0];
  const float* W_ih1 = (const float*)d_in[1];
  const float* W_hh1 = (const float*)d_in[2];
  const float* b_ih1 = (const float*)d_in[3];
  const float* b_hh1 = (const float*)d_in[4];
  const float* W_ih2 = (const float*)d_in[5];
  const float* W_hh2 = (const float*)d_in[6];
  const float* b_ih2 = (const float*)d_in[7];
  const float* b_hh2 = (const float*)d_in[8];
  const float* W_ih3 = (const float*)d_in[9];
  const float* W_hh3 = (const float*)d_in[10];
  const float* b_ih3 = (const float*)d_in[11];
  const float* b_hh3 = (const float*)d_in[12];
  const float* W_d   = (const float*)d_in[13];
  const float* b_d   = (const float*)d_in[14];
  float* out = (float*)d_out;
  (void)in_sizes; (void)n_in; (void)out_size; (void)ws_size;

  char* ws = (char*)d_ws;
  size_t off = 0;
  auto alloc = [&](size_t bytes) -> char* {
    char* pp = ws + off;
    off = (off + bytes + 255) & ~(size_t)255;
    return pp;
  };

  const int nwih1 = 3 * H1 * F,  nwhh1 = 3 * H1 * H1;
  const int nwih2 = 3 * H2 * H1, nwhh2 = 3 * H2 * H2;
  const int nwih3 = 3 * H3 * H2, nwhh3 = 3 * H3 * H3;

  // total workspace ~65 MB (chunked pipeline)
  short* wih1 = (short*)alloc((size_t)nwih1 * 2);
  short* whh1 = (short*)alloc((size_t)nwhh1 * 2);
  short* wih2 = (short*)alloc((size_t)nwih2 * 2);
  short* whh2 = (short*)alloc((size_t)nwhh2 * 2);
  short* wih3 = (short*)alloc((size_t)nwih3 * 2);
  short* whh3 = (short*)alloc((size_t)nwhh3 * 2);
  short* h1c  = (short*)alloc((size_t)B * TC * H1 * 2);                  // 16.8 MB
  short* h2c  = (short*)alloc((size_t)B * TC * H2 * 2);                  //  8.4 MB
  short* xgT2 = (short*)alloc(((size_t)(B / 16) * TC + 1) * 3 * H2 * 16 * 2);  // 25.2 MB
  short* xgT3 = (short*)alloc(((size_t)(B / 16) * TC + 1) * 3 * H3 * 16 * 2);  // 12.6 MB
  float* car1 = (float*)alloc((size_t)B * H1 * 4);
  float* car2 = (float*)alloc((size_t)B * H2 * 4);
  float* car3 = (float*)alloc((size_t)B * H3 * 4);
  float* hlast = (float*)alloc((size_t)B * H3 * 4);

  CastArgs ca;
  ca.d[0] = {W_ih1, wih1, nwih1};
  ca.d[1] = {W_hh1, whh1, nwhh1};
  ca.d[2] = {W_ih2, wih2, nwih2};
  ca.d[3] = {W_hh2, whh2, nwhh2};
  ca.d[4] = {W_ih3, wih3, nwih3};
  ca.d[5] = {W_hh3, whh3, nwhh3};
  cast_many<<<512, 256, 0, stream>>>(ca);

  constexpr int SM1 = (H1 + 2 * 16) * (H1 + 8) * 2;      // 152064
  constexpr int SM2 = (3 * H2 + 2 * 16) * (H2 + 8) * 2;  // 113152
  constexpr int SM3 = (3 * H3 + 2 * 16) * (H3 + 8) * 2;  //  32256

  auto* k1 = gru_l1<TC>;
  auto* k2 = gru_xg<H2, 8, 1, TC, true>;
  auto* k3 = gru_xg<H3, 4, 1, TC, false>;
  (void)hipFuncSetAttribute((const void*)k1, hipFuncAttributeMaxDynamicSharedMemorySize, SM1);
  (void)hipFuncSetAttribute((const void*)k2, hipFuncAttributeMaxDynamicSharedMemorySize, SM2);
  (void)hipFuncSetAttribute((const void*)k3, hipFuncAttributeMaxDynamicSharedMemorySize, SM3);

  for (int c = 0; c < NCHUNK; c++) {
    const int t0 = c * TC;
    k1<<<B / 16, 8 * 64, SM1, stream>>>(x, wih1, whh1, b_ih1, b_hh1, h1c, car1, t0);
    xg_gemm<H1, 3 * H2, TC><<<dim3(TC, B / 16), 256, 0, stream>>>(h1c, wih2, xgT2);
    k2<<<B / 16, 8 * 64, SM2, stream>>>(xgT2, whh2, b_ih2, b_hh2, h2c, car2, nullptr, t0);
    xg_gemm<H2, 3 * H3, TC><<<dim3(TC, B / 16), 256, 0, stream>>>(h2c, wih3, xgT3);
    k3<<<B / 16, 4 * 64, SM3, stream>>>(xgT3, whh3, b_ih3, b_hh3, nullptr, car3, hlast, t0);
  }

  dense_kernel<<<B / 64, 64, 0, stream>>>(hlast, W_d, b_d, out);
}

// Round 9
// 1487.929 us; speedup vs baseline: 1.1544x; 1.1544x over previous
//
#include <hip/hip_runtime.h>
#include <cstddef>

// ---------- types ----------
typedef _Float16 f16x8 __attribute__((ext_vector_type(8)));
typedef short    s16x8 __attribute__((ext_vector_type(8)));
typedef short    s16x4 __attribute__((ext_vector_type(4)));
typedef float    f32x4 __attribute__((ext_vector_type(4)));

#define MFMA_F16(a, b, c) __builtin_amdgcn_mfma_f32_16x16x32_f16((a), (b), (c), 0, 0, 0)

#if __has_builtin(__builtin_amdgcn_sched_barrier)
#define SCHED_FENCE() __builtin_amdgcn_sched_barrier(0)
#else
#define SCHED_FENCE() do {} while (0)
#endif

#if __has_builtin(__builtin_amdgcn_rcpf)
__device__ __forceinline__ float fast_rcp(float x) { return __builtin_amdgcn_rcpf(x); }
#else
__device__ __forceinline__ float fast_rcp(float x) { return 1.f / x; }
#endif

__device__ __forceinline__ f16x8 ld8(const short* p) {
  return __builtin_bit_cast(f16x8, *(const s16x8*)p);
}
__device__ __forceinline__ float s2f(short s) {
  return (float)__builtin_bit_cast(_Float16, s);
}
__device__ __forceinline__ short f2s(float f) {
  return __builtin_bit_cast(short, (_Float16)f);
}

// GRU gate math. Returns h_new.
__device__ __forceinline__ float gru_gate(float rpre, float zpre, float ghn,
                                          float xnb, float hprev) {
  const float rg = fast_rcp(1.f + __expf(-rpre));
  const float zg = fast_rcp(1.f + __expf(-zpre));
  const float narg = xnb + rg * ghn;
  const float e2 = __expf(2.f * narg);
  const float ng = 1.f - 2.f * fast_rcp(e2 + 1.f);  // tanh(narg)
  return (1.f - zg) * ng + zg * hprev;
}

// ---------- fp32 -> fp16 casts (weights only) ----------
struct CastDesc { const float* src; short* dst; int n; };
struct CastArgs { CastDesc d[6]; };

__global__ void cast_many(CastArgs a) {
  const int tid = blockIdx.x * blockDim.x + threadIdx.x;
  const int stride = gridDim.x * blockDim.x;
#pragma unroll
  for (int j = 0; j < 6; j++) {
    const float* __restrict__ s = a.d[j].src;
    short* __restrict__ o = a.d[j].dst;
    const int n = a.d[j].n;
    for (int i = tid; i < n; i += stride) o[i] = f2s(s[i]);
  }
}

// ---------- xg projection GEMM (chunked) ----------
// xgT[(wg*TC+t)][c*16+p][q*4+r] = (A_t @ W^T) in the rec epilogue C-layout.
// A: [B, Tfull, K] (fp32 if AF32 else fp16); W: [NC, K] fp16.
template <int K, int NC, int TC, bool AF32>
__global__ __launch_bounds__(256)
void xg_gemm(const void* __restrict__ Araw, const short* __restrict__ W,
             short* __restrict__ xgT, int t0, int Tfull) {
  constexpr int KF = K / 32;
  const int lane = threadIdx.x & 63, wid = threadIdx.x >> 6;
  const int p = lane & 15, q = lane >> 4;
  const int t = blockIdx.x, wg = blockIdx.y;
  const int b0 = wg * 16;

  f16x8 ax[KF];
  if constexpr (AF32) {
    const float* ap = (const float*)Araw + ((size_t)(b0 + p) * Tfull + (t0 + t)) * K + q * 8;
#pragma unroll
    for (int k = 0; k < KF; k++) {
      const f32x4 a0 = *(const f32x4*)(ap + k * 32);
      const f32x4 a1 = *(const f32x4*)(ap + k * 32 + 4);
      f16x8 v;
#pragma unroll
      for (int i = 0; i < 4; i++) { v[i] = (_Float16)a0[i]; v[4 + i] = (_Float16)a1[i]; }
      ax[k] = v;
    }
  } else {
    const short* ap = (const short*)Araw + ((size_t)(b0 + p) * Tfull + (t0 + t)) * K + q * 8;
#pragma unroll
    for (int k = 0; k < KF; k++) ax[k] = ld8(ap + k * 32);
  }

  short* outb = xgT + ((size_t)wg * TC + t) * NC * 16;
#pragma unroll 1
  for (int c = wid; c < NC / 16; c += 4) {
    const short* wp = W + (size_t)(c * 16 + p) * K + q * 8;
    f32x4 acc = {0.f, 0.f, 0.f, 0.f};
#pragma unroll
    for (int k = 0; k < KF; k++) acc = MFMA_F16(ax[k], ld8(wp + k * 32), acc);
    s16x4 o;
#pragma unroll
    for (int r = 0; r < 4; r++) o[r] = f2s(acc[r]);
    *(s16x4*)&outb[(size_t)(c * 16 + p) * 16 + q * 4] = o;
  }
}

// ---------- L1 recurrence (H=256), chunked, xg precomputed ----------
// whh_n LDS-resident; whh_r/z streamed per step (issue-early, 256-VGPR budget
// via waves_per_eu(2,2) so the 32-fragment stream buffer stays in registers).
template <int TC>
__global__ __launch_bounds__(512)
__attribute__((amdgpu_waves_per_eu(2, 2)))
void gru_l1x(const short* __restrict__ xgT,   // [(32*TC+1)][768][16] fp16
             const short* __restrict__ Whh,   // [768,256] fp16
             const float* __restrict__ b_ih, const float* __restrict__ b_hh,
             short* __restrict__ h1c,         // [B,TC,256] fp16 chunk out
             float* __restrict__ carry,       // [B,256] fp32
             int t0) {
  constexpr int H = 256, NW = 8, JT = 2, KS = 8, HP = H + 8;
  constexpr size_t XGS = (size_t)3 * H * 16;
  extern __shared__ __align__(16) short smem[];
  short* whhL = smem;             // [256][HP] (n-gate rows)
  short* hb   = smem + H * HP;    // [2][16][HP]

  const int tid = threadIdx.x, lane = tid & 63, wid = tid >> 6;
  const int p = lane & 15, q = lane >> 4;
  const int wg = blockIdx.x, b0 = wg * 16, j0 = wid * (16 * JT);

  for (int i = tid; i < H * (H / 8); i += NW * 64) {
    const int row = i / (H / 8), kc = i % (H / 8);
    *(s16x8*)&whhL[row * HP + kc * 8] =
        *(const s16x8*)&Whh[(size_t)(2 * H + row) * H + kc * 8];
  }
  if (t0 == 0) {
    for (int i = tid; i < 2 * 16 * HP; i += NW * 64) hb[i] = 0;
  } else {
    for (int i = tid; i < 16 * H; i += NW * 64) {
      const int row = i >> 8, col = i & (H - 1);
      hb[row * HP + col] = f2s(carry[(size_t)(b0 + row) * H + col]);
    }
  }

  float brz_r[JT], brz_z[JT], bxn[JT], bhn[JT];
  const short* wrz[2][JT];
  const short* xgp[3][JT];
  int wrow[JT];
#pragma unroll
  for (int jt = 0; jt < JT; jt++) {
    const int col = j0 + jt * 16 + p;
    brz_r[jt] = b_ih[col] + b_hh[col];
    brz_z[jt] = b_ih[H + col] + b_hh[H + col];
    bxn[jt]   = b_ih[2 * H + col];
    bhn[jt]   = b_hh[2 * H + col];
    wrow[jt]  = col;
    wrz[0][jt] = Whh + (size_t)(0 * H + col) * H + q * 8;
    wrz[1][jt] = Whh + (size_t)(1 * H + col) * H + q * 8;
#pragma unroll
    for (int g = 0; g < 3; g++)
      xgp[g][jt] = xgT + (size_t)wg * TC * XGS + (size_t)(g * H + col) * 16 + q * 4;
  }
  float hprev[JT][4];
#pragma unroll
  for (int jt = 0; jt < JT; jt++)
#pragma unroll
    for (int r = 0; r < 4; r++)
      hprev[jt][r] = (t0 == 0) ? 0.f
                   : carry[(size_t)(b0 + q * 4 + r) * H + j0 + jt * 16 + p];

  // prime xg prefetch (local t=0)
  s16x4 xgc[3][JT];
#pragma unroll
  for (int g = 0; g < 3; g++)
#pragma unroll
    for (int jt = 0; jt < JT; jt++) xgc[g][jt] = *(const s16x4*)xgp[g][jt];

  __syncthreads();

  for (int t = 0; t < TC; t++) {
    const int cur = t & 1;
    short* hbc = hb + cur * 16 * HP;
    short* hbn = hb + (cur ^ 1) * 16 * HP;

    // issue-early: r/z weight stream + next-step xg prefetch
    f16x8 wst[2][JT][KS];
#pragma unroll
    for (int g = 0; g < 2; g++)
#pragma unroll
      for (int jt = 0; jt < JT; jt++)
#pragma unroll
        for (int k = 0; k < KS; k++) wst[g][jt][k] = ld8(wrz[g][jt] + k * 32);
    s16x4 xgn[3][JT];
    {
      const size_t toff = (size_t)(t + 1) * XGS;  // t=TC-1 reads pad row
#pragma unroll
      for (int g = 0; g < 3; g++)
#pragma unroll
        for (int jt = 0; jt < JT; jt++)
          xgn[g][jt] = *(const s16x4*)(xgp[g][jt] + toff);
    }
    SCHED_FENCE();

    f32x4 ar[JT], az[JT], an[JT];
#pragma unroll
    for (int jt = 0; jt < JT; jt++) {
      ar[jt] = f32x4{0.f, 0.f, 0.f, 0.f};
      az[jt] = f32x4{0.f, 0.f, 0.f, 0.f};
      an[jt] = f32x4{0.f, 0.f, 0.f, 0.f};
    }
    f16x8 ah[KS];
#pragma unroll
    for (int k = 0; k < KS; k++) ah[k] = ld8(&hbc[p * HP + k * 32 + q * 8]);

    // n-gate from LDS first (covers stream latency)
#pragma unroll
    for (int k = 0; k < KS; k++)
#pragma unroll
      for (int jt = 0; jt < JT; jt++)
        an[jt] = MFMA_F16(ah[k], ld8(&whhL[wrow[jt] * HP + k * 32 + q * 8]), an[jt]);
    // streamed r/z
#pragma unroll
    for (int k = 0; k < KS; k++)
#pragma unroll
      for (int jt = 0; jt < JT; jt++) {
        ar[jt] = MFMA_F16(ah[k], wst[0][jt][k], ar[jt]);
        az[jt] = MFMA_F16(ah[k], wst[1][jt][k], az[jt]);
      }

#pragma unroll
    for (int jt = 0; jt < JT; jt++)
#pragma unroll
      for (int r = 0; r < 4; r++) {
        const int bm = q * 4 + r;
        const int col = j0 + jt * 16 + p;
        const float hnew = gru_gate(ar[jt][r] + s2f(xgc[0][jt][r]) + brz_r[jt],
                                    az[jt][r] + s2f(xgc[1][jt][r]) + brz_z[jt],
                                    an[jt][r] + bhn[jt],
                                    s2f(xgc[2][jt][r]) + bxn[jt], hprev[jt][r]);
        hprev[jt][r] = hnew;
        const short hf = f2s(hnew);
        hbn[bm * HP + col] = hf;
        h1c[((size_t)(b0 + bm) * TC + t) * H + col] = hf;
      }
#pragma unroll
    for (int g = 0; g < 3; g++)
#pragma unroll
      for (int jt = 0; jt < JT; jt++) xgc[g][jt] = xgn[g][jt];
    __syncthreads();
  }
#pragma unroll
  for (int jt = 0; jt < JT; jt++)
#pragma unroll
    for (int r = 0; r < 4; r++)
      carry[(size_t)(b0 + q * 4 + r) * H + j0 + jt * 16 + p] = hprev[jt][r];
}

// ---------- L2/L3 recurrence: whh fully LDS-resident + precomputed xg ----------
template <int H, int NW, int JT, int TC, bool STORE_SEQ>
__global__ __launch_bounds__(NW * 64)
void gru_xg(const short* __restrict__ xgT,   // [(32*TC+1)][3H][16] fp16
            const short* __restrict__ Whh,   // [3H,H] fp16
            const float* __restrict__ b_ih, const float* __restrict__ b_hh,
            short* __restrict__ hseqc,       // [B,TC,H] fp16 (STORE_SEQ)
            float* __restrict__ carry,       // [B,H] fp32
            float* __restrict__ hlast,       // [B,H] fp32 (!STORE_SEQ)
            int t0) {
  static_assert(NW * 16 * JT == H, "tiling must cover H");
  constexpr int KS = H / 32, HP = H + 8;
  constexpr size_t XGS = (size_t)3 * H * 16;
  extern __shared__ __align__(16) short smem[];
  short* whhL = smem;                 // [3H][HP]
  short* hb   = smem + 3 * H * HP;    // [2][16][HP]

  const int tid = threadIdx.x, lane = tid & 63, wid = tid >> 6;
  const int p = lane & 15, q = lane >> 4;
  const int wg = blockIdx.x, b0 = wg * 16, j0 = wid * (16 * JT);

  for (int i = tid; i < 3 * H * (H / 8); i += NW * 64) {
    const int row = i / (H / 8), kc = i % (H / 8);
    *(s16x8*)&whhL[row * HP + kc * 8] = *(const s16x8*)&Whh[(size_t)row * H + kc * 8];
  }
  if (t0 == 0) {
    for (int i = tid; i < 2 * 16 * HP; i += NW * 64) hb[i] = 0;
  } else {
    for (int i = tid; i < 16 * H; i += NW * 64) {
      const int row = i / H, col = i % H;
      hb[row * HP + col] = f2s(carry[(size_t)(b0 + row) * H + col]);
    }
  }

  float brz_r[JT], brz_z[JT], bxn[JT], bhn[JT];
  int wrow[JT];
  const short* xgp[3][JT];
#pragma unroll
  for (int jt = 0; jt < JT; jt++) {
    const int col = j0 + jt * 16 + p;
    brz_r[jt] = b_ih[col] + b_hh[col];
    brz_z[jt] = b_ih[H + col] + b_hh[H + col];
    bxn[jt]   = b_ih[2 * H + col];
    bhn[jt]   = b_hh[2 * H + col];
    wrow[jt]  = col;
#pragma unroll
    for (int g = 0; g < 3; g++)
      xgp[g][jt] = xgT + (size_t)wg * TC * XGS + (size_t)(g * H + col) * 16 + q * 4;
  }
  float hprev[JT][4];
#pragma unroll
  for (int jt = 0; jt < JT; jt++)
#pragma unroll
    for (int r = 0; r < 4; r++)
      hprev[jt][r] = (t0 == 0) ? 0.f
                   : carry[(size_t)(b0 + q * 4 + r) * H + j0 + jt * 16 + p];

  s16x4 xgc[3][JT];
#pragma unroll
  for (int g = 0; g < 3; g++)
#pragma unroll
    for (int jt = 0; jt < JT; jt++) xgc[g][jt] = *(const s16x4*)xgp[g][jt];

  __syncthreads();

  for (int t = 0; t < TC; t++) {
    const int cur = t & 1;
    short* hbc = hb + cur * 16 * HP;
    short* hbn = hb + (cur ^ 1) * 16 * HP;

    s16x4 xgn[3][JT];
    {
      const size_t toff = (size_t)(t + 1) * XGS;
#pragma unroll
      for (int g = 0; g < 3; g++)
#pragma unroll
        for (int jt = 0; jt < JT; jt++)
          xgn[g][jt] = *(const s16x4*)(xgp[g][jt] + toff);
    }

    f32x4 ar[JT], az[JT], an[JT];
#pragma unroll
    for (int jt = 0; jt < JT; jt++) {
      ar[jt] = f32x4{0.f, 0.f, 0.f, 0.f};
      az[jt] = f32x4{0.f, 0.f, 0.f, 0.f};
      an[jt] = f32x4{0.f, 0.f, 0.f, 0.f};
    }
    f16x8 ah[KS];
#pragma unroll
    for (int k = 0; k < KS; k++) ah[k] = ld8(&hbc[p * HP + k * 32 + q * 8]);

#pragma unroll
    for (int k = 0; k < KS; k++)
#pragma unroll
      for (int jt = 0; jt < JT; jt++) {
        ar[jt] = MFMA_F16(ah[k], ld8(&whhL[(0 * H + wrow[jt]) * HP + k * 32 + q * 8]), ar[jt]);
        az[jt] = MFMA_F16(ah[k], ld8(&whhL[(1 * H + wrow[jt]) * HP + k * 32 + q * 8]), az[jt]);
        an[jt] = MFMA_F16(ah[k], ld8(&whhL[(2 * H + wrow[jt]) * HP + k * 32 + q * 8]), an[jt]);
      }

#pragma unroll
    for (int jt = 0; jt < JT; jt++)
#pragma unroll
      for (int r = 0; r < 4; r++) {
        const int bm = q * 4 + r;
        const int col = j0 + jt * 16 + p;
        const float hnew = gru_gate(ar[jt][r] + s2f(xgc[0][jt][r]) + brz_r[jt],
                                    az[jt][r] + s2f(xgc[1][jt][r]) + brz_z[jt],
                                    an[jt][r] + bhn[jt],
                                    s2f(xgc[2][jt][r]) + bxn[jt], hprev[jt][r]);
        hprev[jt][r] = hnew;
        const short hf = f2s(hnew);
        hbn[bm * HP + col] = hf;
        if (STORE_SEQ) {
          hseqc[((size_t)(b0 + bm) * TC + t) * H + col] = hf;
        } else if (t0 + t == 255) {
          hlast[(size_t)(b0 + bm) * H + col] = hnew;
        }
      }
#pragma unroll
    for (int g = 0; g < 3; g++)
#pragma unroll
      for (int jt = 0; jt < JT; jt++) xgc[g][jt] = xgn[g][jt];
    __syncthreads();
  }
#pragma unroll
  for (int jt = 0; jt < JT; jt++)
#pragma unroll
    for (int r = 0; r < 4; r++)
      carry[(size_t)(b0 + q * 4 + r) * H + j0 + jt * 16 + p] = hprev[jt][r];
}

// ---------- dense head ----------
__global__ void dense_kernel(const float* __restrict__ hl, const float* __restrict__ Wd,
                             const float* __restrict__ bd, float* __restrict__ out) {
  const int b = blockIdx.x * 64 + threadIdx.x;
  float a = bd[0];
#pragma unroll
  for (int k = 0; k < 64; k++) a = fmaf(hl[b * 64 + k], Wd[k], a);
  out[b] = a;
}

// ---------- host ----------
extern "C" void kernel_launch(void* const* d_in, const int* in_sizes, int n_in,
                              void* d_out, int out_size, void* d_ws, size_t ws_size,
                              hipStream_t stream) {
  constexpr int B = 512, T = 256;
  constexpr int H1 = 256, H2 = 128, H3 = 64, F = 64;
  constexpr int TC = 64, NCHUNK = T / TC;

  const float* x     = (const float*)d_in[0];
  const float* W_ih1 = (const float*)d_in[1];
  const float* W_hh1 = (const float*)d_in[2];
  const float* b_ih1 = (const float*)d_in[3];
  const float* b_hh1 = (const float*)d_in[4];
  const float* W_ih2 = (const float*)d_in[5];
  const float* W_hh2 = (const float*)d_in[6];
  const float* b_ih2 = (const float*)d_in[7];
  const float* b_hh2 = (const float*)d_in[8];
  const float* W_ih3 = (const float*)d_in[9];
  const float* W_hh3 = (const float*)d_in[10];
  const float* b_ih3 = (const float*)d_in[11];
  const float* b_hh3 = (const float*)d_in[12];
  const float* W_d   = (const float*)d_in[13];
  const float* b_d   = (const float*)d_in[14];
  float* out = (float*)d_out;
  (void)in_sizes; (void)n_in; (void)out_size; (void)ws_size;

  char* ws = (char*)d_ws;
  size_t off = 0;
  auto alloc = [&](size_t bytes) -> char* {
    char* pp = ws + off;
    off = (off + bytes + 255) & ~(size_t)255;
    return pp;
  };

  const int nwih1 = 3 * H1 * F,  nwhh1 = 3 * H1 * H1;
  const int nwih2 = 3 * H2 * H1, nwhh2 = 3 * H2 * H2;
  const int nwih3 = 3 * H3 * H2, nwhh3 = 3 * H3 * H3;

  // workspace ~79 MB: one xg buffer reused by all three layers
  short* wih1 = (short*)alloc((size_t)nwih1 * 2);
  short* whh1 = (short*)alloc((size_t)nwhh1 * 2);
  short* wih2 = (short*)alloc((size_t)nwih2 * 2);
  short* whh2 = (short*)alloc((size_t)nwhh2 * 2);
  short* wih3 = (short*)alloc((size_t)nwih3 * 2);
  short* whh3 = (short*)alloc((size_t)nwhh3 * 2);
  short* h1c  = (short*)alloc((size_t)B * TC * H1 * 2);            // 16.8 MB
  short* h2c  = (short*)alloc((size_t)B * TC * H2 * 2);            //  8.4 MB
  const size_t xg1_bytes = ((size_t)(B / 16) * TC + 1) * 3 * H1 * 16 * 2;  // 50.4 MB
  short* xgbuf = (short*)alloc(xg1_bytes);
  short* xgT1 = xgbuf;
  short* xgT2 = xgbuf;                                   // reused after k1
  short* xgT3 = (short*)((char*)xgbuf + 26u * 1024 * 1024);  // disjoint from xgT2
  float* car1 = (float*)alloc((size_t)B * H1 * 4);
  float* car2 = (float*)alloc((size_t)B * H2 * 4);
  float* car3 = (float*)alloc((size_t)B * H3 * 4);
  float* hlast = (float*)alloc((size_t)B * H3 * 4);

  CastArgs ca;
  ca.d[0] = {W_ih1, wih1, nwih1};
  ca.d[1] = {W_hh1, whh1, nwhh1};
  ca.d[2] = {W_ih2, wih2, nwih2};
  ca.d[3] = {W_hh2, whh2, nwhh2};
  ca.d[4] = {W_ih3, wih3, nwih3};
  ca.d[5] = {W_hh3, whh3, nwhh3};
  cast_many<<<512, 256, 0, stream>>>(ca);

  constexpr int SM1 = (H1 + 2 * 16) * (H1 + 8) * 2;      // 152064
  constexpr int SM2 = (3 * H2 + 2 * 16) * (H2 + 8) * 2;  // 113152
  constexpr int SM3 = (3 * H3 + 2 * 16) * (H3 + 8) * 2;  //  32256

  auto* k1 = gru_l1x<TC>;
  auto* k2 = gru_xg<H2, 8, 1, TC, true>;
  auto* k3 = gru_xg<H3, 4, 1, TC, false>;
  (void)hipFuncSetAttribute((const void*)k1, hipFuncAttributeMaxDynamicSharedMemorySize, SM1);
  (void)hipFuncSetAttribute((const void*)k2, hipFuncAttributeMaxDynamicSharedMemorySize, SM2);
  (void)hipFuncSetAttribute((const void*)k3, hipFuncAttributeMaxDynamicSharedMemorySize, SM3);

  for (int c = 0; c < NCHUNK; c++) {
    const int t0 = c * TC;
    xg_gemm<F, 3 * H1, TC, true><<<dim3(TC, B / 16), 256, 0, stream>>>(x, wih1, xgT1, t0, T);
    k1<<<B / 16, 8 * 64, SM1, stream>>>(xgT1, whh1, b_ih1, b_hh1, h1c, car1, t0);
    xg_gemm<H1, 3 * H2, TC, false><<<dim3(TC, B / 16), 256, 0, stream>>>(h1c, wih2, xgT2, 0, TC);
    k2<<<B / 16, 8 * 64, SM2, stream>>>(xgT2, whh2, b_ih2, b_hh2, h2c, car2, nullptr, t0);
    xg_gemm<H2, 3 * H3, TC, false><<<dim3(TC, B / 16), 256, 0, stream>>>(h2c, wih3, xgT3, 0, TC);
    k3<<<B / 16, 4 * 64, SM3, stream>>>(xgT3, whh3, b_ih3, b_hh3, nullptr, car3, hlast, t0);
  }

  dense_kernel<<<B / 64, 64, 0, stream>>>(hlast, W_d, b_d, out);
}